// Round 2
// baseline (118.680 us; speedup 1.0000x reference)
//
#include <hip/hip_runtime.h>

#define BB 32
#define NN 1024
#define MM 1024
#define DD 128

typedef __attribute__((ext_vector_type(4))) float f32x4;
typedef __attribute__((ext_vector_type(8))) __bf16 bf16x8;
typedef unsigned short ushort_t;

__device__ __forceinline__ unsigned f2bf(float x) {
    unsigned u = __builtin_bit_cast(unsigned, x);
    return (u + 0x7fffu + ((u >> 16) & 1u)) >> 16;  // RNE bf16, finite inputs
}
__device__ __forceinline__ float leaky(float x) { return fmaxf(x, 0.2f * x); }

// ---------------- Kernel A: e1[b,n] = h[b,n,:]·a1 ; e2[b,m] = g[b,m,:]·a2 ----
__global__ __launch_bounds__(256) void compute_e(
    const float* __restrict__ h, const float* __restrict__ g,
    const float* __restrict__ a1, const float* __restrict__ a2,
    float* __restrict__ e1, float* __restrict__ e2)
{
    int wave = (blockIdx.x * 256 + threadIdx.x) >> 6;
    int lane = threadIdx.x & 63;
    const float* src; const float* av; float* dst; int row = wave;
    if (wave < BB * NN) { src = h; av = a1; dst = e1; }
    else { row -= BB * NN; src = g; av = a2; dst = e2; }
    float2 x = *(const float2*)(src + (size_t)row * DD + lane * 2);
    float2 a = *(const float2*)(av + lane * 2);
    float p = x.x * a.x + x.y * a.y;
    #pragma unroll
    for (int s = 32; s; s >>= 1) p += __shfl_xor(p, s);
    if (lane == 0) dst[row] = p;
}

// ---------------- Kernel B: per-batch max of e2 ------------------------------
__global__ __launch_bounds__(256) void compute_e2max(
    const float* __restrict__ e2, float* __restrict__ e2max)
{
    int b = blockIdx.x, t = threadIdx.x;
    float m = -1e30f;
    for (int i = t; i < MM; i += 256) m = fmaxf(m, e2[b * MM + i]);
    #pragma unroll
    for (int s = 32; s; s >>= 1) m = fmaxf(m, __shfl_xor(m, s));
    __shared__ float sm[4];
    if ((t & 63) == 0) sm[t >> 6] = m;
    __syncthreads();
    if (t == 0) e2max[b] = fmaxf(fmaxf(sm[0], sm[1]), fmaxf(sm[2], sm[3]));
}

// ---------------- Kernel T: gbfT[b][d][m] = bf16(g[b][m][d]) -----------------
__global__ __launch_bounds__(256) void transpose_g(
    const float* __restrict__ g, ushort_t* __restrict__ gbfT)
{
    __shared__ ushort_t tl[DD][66];  // +2 pad breaks write bank conflicts
    int b = blockIdx.y, m0 = blockIdx.x * 64, t = threadIdx.x;
    #pragma unroll
    for (int i = 0; i < 8; i++) {
        int idx = i * 256 + t;
        int m = idx >> 5;            // 0..63
        int c4 = (idx & 31) * 4;     // d col 0..124
        float4 v = *(const float4*)(g + ((size_t)(b * MM + m0 + m)) * DD + c4);
        tl[c4 + 0][m] = (ushort_t)f2bf(v.x);
        tl[c4 + 1][m] = (ushort_t)f2bf(v.y);
        tl[c4 + 2][m] = (ushort_t)f2bf(v.z);
        tl[c4 + 3][m] = (ushort_t)f2bf(v.w);
    }
    __syncthreads();
    #pragma unroll
    for (int i = 0; i < 4; i++) {
        int idx = i * 256 + t;
        int d = idx >> 3;            // 0..127
        int c = (idx & 7) * 8;       // 0..56
        int4 o;
        o.x = (int)((unsigned)tl[d][c + 0] | ((unsigned)tl[d][c + 1] << 16));
        o.y = (int)((unsigned)tl[d][c + 2] | ((unsigned)tl[d][c + 3] << 16));
        o.z = (int)((unsigned)tl[d][c + 4] | ((unsigned)tl[d][c + 5] << 16));
        o.w = (int)((unsigned)tl[d][c + 6] | ((unsigned)tl[d][c + 7] << 16));
        *(int4*)(gbfT + ((size_t)(b * DD + d)) * MM + m0 + c) = o;
    }
}

// ---------------- Main: fused mask+softmax+PV, no LDS, no barriers -----------
// block = 256 (4 waves). Each wave owns 16 rows x all 128 d.
// Lane computes its OWN A-fragment: row = lane&15, k = 8*(lane>>4)+j.
__global__ __launch_bounds__(256) void attn_main(
    const int* __restrict__ adj, const ushort_t* __restrict__ gbfT,
    const float* __restrict__ e1, const float* __restrict__ e2,
    const float* __restrict__ e2max, float* __restrict__ out)
{
    int b = blockIdx.y, t = threadIdx.x;
    int wid = t >> 6, lane = t & 63;
    int rlo = lane & 15, h = lane >> 4;
    int row = blockIdx.x * 64 + wid * 16 + rlo;

    float e2m = e2max[b];
    float e1r = e1[b * NN + row];
    float Cr = leaky(e1r + e2m);     // >= every e in this row (leaky monotone)

    const int* aptr = adj + ((size_t)(b * NN + row)) * MM + 8 * h;
    const float* eptr = e2 + b * MM + 8 * h;
    const ushort_t* gb = gbfT + (size_t)b * DD * MM + (size_t)rlo * MM + 8 * h;

    f32x4 acc[8];
    #pragma unroll
    for (int j = 0; j < 8; j++) acc[j] = (f32x4){0.f, 0.f, 0.f, 0.f};

    float zl = 0.f, dl = 0.f;

    int4 ca0 = *(const int4*)(aptr + 0);
    int4 ca1 = *(const int4*)(aptr + 4);

    for (int mc = 0; mc < 32; ++mc) {
        int4 na0, na1;
        if (mc < 31) {
            na0 = *(const int4*)(aptr + (mc + 1) * 32);
            na1 = *(const int4*)(aptr + (mc + 1) * 32 + 4);
        }
        float4 ev0 = *(const float4*)(eptr + mc * 32);
        float4 ev1 = *(const float4*)(eptr + mc * 32 + 4);

        int   ax[8] = {ca0.x, ca0.y, ca0.z, ca0.w, ca1.x, ca1.y, ca1.z, ca1.w};
        float ex[8] = {ev0.x, ev0.y, ev0.z, ev0.w, ev1.x, ev1.y, ev1.z, ev1.w};
        bf16x8 af;
        #pragma unroll
        for (int jj = 0; jj < 8; jj++) {
            float s = leaky(e1r + ex[jj]) - Cr;
            float wv = (ax[jj] > 0) ? __expf(s) : 0.f;
            zl += wv;
            dl += (ax[jj] > 0) ? 1.f : 0.f;
            af[jj] = (__bf16)wv;
        }

        const ushort_t* gp = gb + mc * 32;
        #pragma unroll
        for (int j = 0; j < 8; j++) {
            bf16x8 bv = __builtin_bit_cast(bf16x8,
                        *(const int4*)(gp + (size_t)j * 16 * MM));
            acc[j] = __builtin_amdgcn_mfma_f32_16x16x32_bf16(af, bv, acc[j], 0, 0, 0);
        }
        if (mc < 31) { ca0 = na0; ca1 = na1; }
    }

    // per-row Z and deg live in lanes sharing (lane&15): reduce over bits 4,5
    zl += __shfl_xor(zl, 16); zl += __shfl_xor(zl, 32);
    dl += __shfl_xor(dl, 16); dl += __shfl_xor(dl, 32);
    float scale = (dl > 0.f) ? (dl / zl) : 0.f;

    // C layout: col = lane&15, row = 4*(lane>>4)+reg. Fetch scale for my 4 rows.
    float sc[4];
    #pragma unroll
    for (int rg = 0; rg < 4; rg++) sc[rg] = __shfl(scale, 4 * h + rg);

    float* ob = out + ((size_t)(b * NN + blockIdx.x * 64 + wid * 16)) * DD + rlo;
    #pragma unroll
    for (int j = 0; j < 8; j++)
        #pragma unroll
        for (int rg = 0; rg < 4; rg++)
            ob[(size_t)(4 * h + rg) * DD + j * 16] = acc[j][rg] * sc[rg];
}

extern "C" void kernel_launch(void* const* d_in, const int* in_sizes, int n_in,
                              void* d_out, int out_size, void* d_ws, size_t ws_size,
                              hipStream_t stream) {
    const float* h   = (const float*)d_in[0];
    const float* g   = (const float*)d_in[1];
    const int*   adj = (const int*)d_in[2];
    const float* a1  = (const float*)d_in[3];
    const float* a2  = (const float*)d_in[4];
    float* out = (float*)d_out;

    // workspace layout
    float* e1  = (float*)d_ws;                        // 32k floats
    float* e2  = e1 + BB * NN;                        // 32k floats
    float* e2m = e2 + BB * MM;                        // 32 floats
    ushort_t* gbfT = (ushort_t*)((char*)d_ws + (1u << 19));  // 8 MB

    compute_e<<<dim3((2 * BB * NN) / (256 / 64)), 256, 0, stream>>>(h, g, a1, a2, e1, e2);
    transpose_g<<<dim3(MM / 64, BB), 256, 0, stream>>>(g, gbfT);
    compute_e2max<<<dim3(BB), 256, 0, stream>>>(e2, e2m);
    attn_main<<<dim3(NN / 64, BB), 256, 0, stream>>>(adj, gbfT, e1, e2, e2m, out);
}

// Round 3
// 71.872 us; speedup vs baseline: 1.6513x; 1.6513x over previous
//
#include <hip/hip_runtime.h>

#define BB 32
#define NN 1024
#define MM 1024
#define DD 128

typedef __attribute__((ext_vector_type(4))) float f32x4;
typedef __attribute__((ext_vector_type(8))) __bf16 bf16x8;
typedef unsigned short ushort_t;
typedef unsigned int uint_t;

#define CBOUND 30.0f

__device__ __forceinline__ unsigned f2bf(float x) {
    unsigned u = __builtin_bit_cast(unsigned, x);
    return (u + 0x7fffu + ((u >> 16) & 1u)) >> 16;  // RNE bf16, finite inputs
}
__device__ __forceinline__ float leaky(float x) { return fmaxf(x, 0.2f * x); }

// ---------------- Kernel 1: e1[b,n] = h[b,n,:]·a1 ----------------------------
__global__ __launch_bounds__(256) void compute_e1(
    const float* __restrict__ h, const float* __restrict__ a1,
    float* __restrict__ e1)
{
    int wave = (blockIdx.x * 256 + threadIdx.x) >> 6;
    int lane = threadIdx.x & 63;
    float2 x = *(const float2*)(h + (size_t)wave * DD + lane * 2);
    float2 a = *(const float2*)(a1 + lane * 2);
    float p = x.x * a.x + x.y * a.y;
    #pragma unroll
    for (int s = 32; s; s >>= 1) p += __shfl_xor(p, s);
    if (lane == 0) e1[wave] = p;
}

// ---------------- Kernel 2: gq[b][mc][d][mm] = bf16(g[b][m][d]); e2 = g·a2 ---
__global__ __launch_bounds__(256) void transpose_pack_g(
    const float* __restrict__ g, const float* __restrict__ a2,
    ushort_t* __restrict__ gq, float* __restrict__ e2)
{
    __shared__ ushort_t tl[DD][66];
    int b = blockIdx.y, m0 = blockIdx.x * 64, t = threadIdx.x;
    #pragma unroll
    for (int i = 0; i < 8; i++) {
        int idx = i * 256 + t;
        int m = idx >> 5;            // local m 0..63 (32 consecutive lanes share m)
        int c4 = (idx & 31) * 4;     // d col 0..124
        float4 v = *(const float4*)(g + ((size_t)(b * MM + m0 + m)) * DD + c4);
        tl[c4 + 0][m] = (ushort_t)f2bf(v.x);
        tl[c4 + 1][m] = (ushort_t)f2bf(v.y);
        tl[c4 + 2][m] = (ushort_t)f2bf(v.z);
        tl[c4 + 3][m] = (ushort_t)f2bf(v.w);
        // e2 partial dot: reduce across the 32 lanes sharing m
        float4 av = *(const float4*)(a2 + c4);
        float p = v.x * av.x + v.y * av.y + v.z * av.z + v.w * av.w;
        #pragma unroll
        for (int s = 16; s; s >>= 1) p += __shfl_xor(p, s);
        if ((t & 31) == 0) e2[b * MM + m0 + m] = p;
    }
    __syncthreads();
    #pragma unroll
    for (int i = 0; i < 4; i++) {
        int idx = i * 256 + t;
        int d = idx >> 3;            // 0..127
        int c = (idx & 7) * 8;       // local m group 0..56
        int4 o;
        o.x = (int)((unsigned)tl[d][c + 0] | ((unsigned)tl[d][c + 1] << 16));
        o.y = (int)((unsigned)tl[d][c + 2] | ((unsigned)tl[d][c + 3] << 16));
        o.z = (int)((unsigned)tl[d][c + 4] | ((unsigned)tl[d][c + 5] << 16));
        o.w = (int)((unsigned)tl[d][c + 6] | ((unsigned)tl[d][c + 7] << 16));
        int mg = m0 + c;
        *(int4*)(gq + (((size_t)((b * 32 + (mg >> 5)) * DD + d)) << 5) + (mg & 31)) = o;
    }
}

// ---------------- Kernel 3: pack adj -> bitmask + degree ---------------------
// One wave per row: 4 x int4 linear loads (1 KB/instr), nibble + shuffle-OR.
__global__ __launch_bounds__(256) void pack_adj(
    const int* __restrict__ adj, uint_t* __restrict__ maskw,
    float* __restrict__ degf)
{
    int wave = (blockIdx.x * 256 + threadIdx.x) >> 6;  // row id 0..32767
    int lane = threadIdx.x & 63;
    const int* ap = adj + (size_t)wave * MM + lane * 4;
    int4 v[4];
    #pragma unroll
    for (int r = 0; r < 4; r++) v[r] = *(const int4*)(ap + r * 256);
    int cnt = 0;
    #pragma unroll
    for (int r = 0; r < 4; r++) {
        uint_t nib = (v[r].x > 0 ? 1u : 0u) | (v[r].y > 0 ? 2u : 0u)
                   | (v[r].z > 0 ? 4u : 0u) | (v[r].w > 0 ? 8u : 0u);
        cnt += __popc(nib);
        uint_t val = nib << (4 * (lane & 7));
        val |= __shfl_xor(val, 1);
        val |= __shfl_xor(val, 2);
        val |= __shfl_xor(val, 4);
        // word w = r*8 + lane>>3 covers m = 32*w .. 32*w+31, bit = m&31
        if ((lane & 7) == 0) maskw[(size_t)wave * 32 + r * 8 + (lane >> 3)] = val;
    }
    #pragma unroll
    for (int s = 32; s; s >>= 1) cnt += __shfl_xor(cnt, s);
    if (lane == 0) degf[wave] = (float)cnt;
}

// ---------------- Kernel 4: fused softmax + PV (all inputs cache-resident) ---
// block = 4 waves, 64 rows, all 128 d. Lane owns its A-fragment:
// row = lane&15, k = 8*(lane>>4)+jj. B double-buffered in registers.
__global__ __launch_bounds__(256) void attn_main(
    const uint_t* __restrict__ maskw, const float* __restrict__ degf,
    const ushort_t* __restrict__ gq, const float* __restrict__ e1,
    const float* __restrict__ e2, float* __restrict__ out)
{
    __shared__ uint_t maskS[64][33];          // pad 33: bank = (r*33+mc)&31
    __shared__ __align__(16) float e2S[MM];
    __shared__ float degS[64];

    int b = blockIdx.y, n0 = blockIdx.x * 64, t = threadIdx.x;
    int wid = t >> 6, lane = t & 63;
    int rlo = lane & 15, hh = lane >> 4;
    int r_w = wid * 16 + rlo;

    // stage e2 row (4 KB)
    *(float4*)(&e2S[t * 4]) = *(const float4*)(e2 + b * MM + t * 4);
    // stage mask: 64 rows x 32 words
    {
        int row = t >> 2, c0 = (t & 3) * 8;
        const uint_t* mp = maskw + (size_t)(b * NN + n0 + row) * 32 + c0;
        uint4 w0 = *(const uint4*)mp;
        uint4 w1 = *(const uint4*)(mp + 4);
        maskS[row][c0 + 0] = w0.x; maskS[row][c0 + 1] = w0.y;
        maskS[row][c0 + 2] = w0.z; maskS[row][c0 + 3] = w0.w;
        maskS[row][c0 + 4] = w1.x; maskS[row][c0 + 5] = w1.y;
        maskS[row][c0 + 6] = w1.z; maskS[row][c0 + 7] = w1.w;
    }
    if (t < 64) degS[t] = degf[b * NN + n0 + t];
    __syncthreads();

    float e1r = e1[b * NN + n0 + r_w];

    const ushort_t* gb = gq + (size_t)b * 32 * DD * 32;
    int loff = rlo * 32 + 8 * hh;             // within-tile offset for j=0

    f32x4 acc[8];
    #pragma unroll
    for (int j = 0; j < 8; j++) acc[j] = (f32x4){0.f, 0.f, 0.f, 0.f};
    float zl = 0.f;

    bf16x8 cb[8];
    #pragma unroll
    for (int j = 0; j < 8; j++)
        cb[j] = __builtin_bit_cast(bf16x8, *(const int4*)(gb + j * 512 + loff));

    for (int mc = 0; mc < 32; ++mc) {
        // prefetch next B tile into registers (batched, independent)
        bf16x8 nb[8];
        int mcn = (mc < 31) ? mc + 1 : 31;
        const ushort_t* gt = gb + (size_t)mcn * (DD * 32);
        #pragma unroll
        for (int j = 0; j < 8; j++)
            nb[j] = __builtin_bit_cast(bf16x8, *(const int4*)(gt + j * 512 + loff));

        uint_t mw = maskS[r_w][mc];
        float4 ev0 = *(const float4*)(&e2S[mc * 32 + 8 * hh]);
        float4 ev1 = *(const float4*)(&e2S[mc * 32 + 8 * hh + 4]);
        float ex[8] = {ev0.x, ev0.y, ev0.z, ev0.w, ev1.x, ev1.y, ev1.z, ev1.w};
        uint_t byte = mw >> (8 * hh);
        bf16x8 af;
        #pragma unroll
        for (int jj = 0; jj < 8; jj++) {
            float s = leaky(e1r + ex[jj]) - CBOUND;
            float wv = ((byte >> jj) & 1u) ? __expf(s) : 0.f;
            zl += wv;
            af[jj] = (__bf16)wv;
        }
        #pragma unroll
        for (int j = 0; j < 8; j++)
            acc[j] = __builtin_amdgcn_mfma_f32_16x16x32_bf16(af, cb[j], acc[j], 0, 0, 0);
        #pragma unroll
        for (int j = 0; j < 8; j++) cb[j] = nb[j];
    }

    // Z lives split across hh groups of same rlo: reduce bits 4,5
    zl += __shfl_xor(zl, 16); zl += __shfl_xor(zl, 32);
    float dg = degS[r_w];
    float scale = (dg > 0.f) ? (dg / zl) : 0.f;
    // C layout: col = rlo, row = 4*hh+rg; fetch scale of rows 4*hh+rg
    float sc[4];
    #pragma unroll
    for (int rg = 0; rg < 4; rg++) sc[rg] = __shfl(scale, 4 * hh + rg);

    float* ob = out + ((size_t)(b * NN + n0 + wid * 16)) * DD + rlo;
    #pragma unroll
    for (int j = 0; j < 8; j++)
        #pragma unroll
        for (int rg = 0; rg < 4; rg++)
            ob[(size_t)(4 * hh + rg) * DD + j * 16] = acc[j][rg] * sc[rg];
}

extern "C" void kernel_launch(void* const* d_in, const int* in_sizes, int n_in,
                              void* d_out, int out_size, void* d_ws, size_t ws_size,
                              hipStream_t stream) {
    const float* h   = (const float*)d_in[0];
    const float* g   = (const float*)d_in[1];
    const int*   adj = (const int*)d_in[2];
    const float* a1  = (const float*)d_in[3];
    const float* a2  = (const float*)d_in[4];
    float* out = (float*)d_out;

    // workspace layout (bytes):
    // e1   @ 0         : 128 KB
    // e2   @ 128 KB    : 128 KB
    // degf @ 256 KB    : 128 KB
    // mask @ 384 KB    : 4 MB
    // gq   @ 4.5 MB    : 8 MB   (total 12.5 MB)
    char* ws = (char*)d_ws;
    float*    e1   = (float*)(ws);
    float*    e2   = (float*)(ws + (128u << 10));
    float*    degf = (float*)(ws + (256u << 10));
    uint_t*   mask = (uint_t*)(ws + (384u << 10));
    ushort_t* gq   = (ushort_t*)(ws + (384u << 10) + (4u << 20));

    pack_adj<<<dim3(BB * NN / 4), 256, 0, stream>>>(adj, mask, degf);
    compute_e1<<<dim3(BB * NN / 4), 256, 0, stream>>>(h, a1, e1);
    transpose_pack_g<<<dim3(MM / 64, BB), 256, 0, stream>>>(g, a2, gq, e2);
    attn_main<<<dim3(NN / 64, BB), 256, 0, stream>>>(mask, degf, gq, e1, e2, out);
}

// Round 5
// 67.569 us; speedup vs baseline: 1.7564x; 1.0637x over previous
//
#include <hip/hip_runtime.h>

#define BB 32
#define NN 1024
#define MM 1024
#define DD 128

typedef __attribute__((ext_vector_type(4))) float f32x4;
typedef __attribute__((ext_vector_type(8))) __bf16 bf16x8;
typedef unsigned short ushort_t;
typedef unsigned int uint_t;

#define CBOUND 30.0f

__device__ __forceinline__ unsigned f2bf(float x) {
    unsigned u = __builtin_bit_cast(unsigned, x);
    return (u + 0x7fffu + ((u >> 16) & 1u)) >> 16;  // RNE bf16, finite inputs
}
__device__ __forceinline__ float leaky(float x) { return fmaxf(x, 0.2f * x); }

// ---- Kernel 1: adj row -> bitmask + degree ; e1[b,n] = h row · a1 (fused) ---
// One wave per row: adj 4x int4 linear loads + h float2, shuffle reductions.
__global__ __launch_bounds__(256) void pack_adj_e1(
    const int* __restrict__ adj, const float* __restrict__ h,
    const float* __restrict__ a1,
    uint_t* __restrict__ maskw, float* __restrict__ degf,
    float* __restrict__ e1)
{
    int wave = (blockIdx.x * 256 + threadIdx.x) >> 6;  // row id 0..32767
    int lane = threadIdx.x & 63;
    const int* ap = adj + (size_t)wave * MM + lane * 4;
    int4 v[4];
    #pragma unroll
    for (int r = 0; r < 4; r++) v[r] = *(const int4*)(ap + r * 256);
    float2 x = *(const float2*)(h + (size_t)wave * DD + lane * 2);
    float2 a = *(const float2*)(a1 + lane * 2);
    float p = x.x * a.x + x.y * a.y;
    int cnt = 0;
    #pragma unroll
    for (int r = 0; r < 4; r++) {
        uint_t nib = (v[r].x > 0 ? 1u : 0u) | (v[r].y > 0 ? 2u : 0u)
                   | (v[r].z > 0 ? 4u : 0u) | (v[r].w > 0 ? 8u : 0u);
        cnt += __popc(nib);
        uint_t val = nib << (4 * (lane & 7));
        val |= __shfl_xor(val, 1);
        val |= __shfl_xor(val, 2);
        val |= __shfl_xor(val, 4);
        if ((lane & 7) == 0) maskw[(size_t)wave * 32 + r * 8 + (lane >> 3)] = val;
    }
    #pragma unroll
    for (int s = 32; s; s >>= 1) {
        cnt += __shfl_xor(cnt, s);
        p   += __shfl_xor(p, s);
    }
    if (lane == 0) { degf[wave] = (float)cnt; e1[wave] = p; }
}

// ---- Kernel 2: gq[b][mc][d][mm] = bf16(g[b][m][d]) ; e2 = g·a2 (fused) ------
__global__ __launch_bounds__(256) void transpose_pack_g(
    const float* __restrict__ g, const float* __restrict__ a2,
    ushort_t* __restrict__ gq, float* __restrict__ e2)
{
    __shared__ ushort_t tl[DD][66];
    int b = blockIdx.y, m0 = blockIdx.x * 64, t = threadIdx.x;
    #pragma unroll
    for (int i = 0; i < 8; i++) {
        int idx = i * 256 + t;
        int m = idx >> 5;            // local m 0..63 (32 consecutive lanes share m)
        int c4 = (idx & 31) * 4;     // d col 0..124
        float4 v = *(const float4*)(g + ((size_t)(b * MM + m0 + m)) * DD + c4);
        tl[c4 + 0][m] = (ushort_t)f2bf(v.x);
        tl[c4 + 1][m] = (ushort_t)f2bf(v.y);
        tl[c4 + 2][m] = (ushort_t)f2bf(v.z);
        tl[c4 + 3][m] = (ushort_t)f2bf(v.w);
        float4 av = *(const float4*)(a2 + c4);
        float p = v.x * av.x + v.y * av.y + v.z * av.z + v.w * av.w;
        #pragma unroll
        for (int s = 16; s; s >>= 1) p += __shfl_xor(p, s);
        if ((t & 31) == 0) e2[b * MM + m0 + m] = p;
    }
    __syncthreads();
    #pragma unroll
    for (int i = 0; i < 4; i++) {
        int idx = i * 256 + t;
        int d = idx >> 3;            // 0..127
        int c = (idx & 7) * 8;       // local m group 0..56
        int4 o;
        o.x = (int)((unsigned)tl[d][c + 0] | ((unsigned)tl[d][c + 1] << 16));
        o.y = (int)((unsigned)tl[d][c + 2] | ((unsigned)tl[d][c + 3] << 16));
        o.z = (int)((unsigned)tl[d][c + 4] | ((unsigned)tl[d][c + 5] << 16));
        o.w = (int)((unsigned)tl[d][c + 6] | ((unsigned)tl[d][c + 7] << 16));
        int mg = m0 + c;
        *(int4*)(gq + (((size_t)((b * 32 + (mg >> 5)) * DD + d)) << 5) + (mg & 31)) = o;
    }
}

// ---- Kernel 3: fused softmax + PV -------------------------------------------
// block = 4 waves = 256 rows x 64 d (dh half). Wave: 64 rows (4 A-frags) x 64 d.
// B-fragment traffic: 1024 waves x 128 KB = 128 MB (L2/L3-resident gq).
// mask/e2/e1/deg staged to LDS once; single barrier; register-dbuf B prefetch.
__global__ __launch_bounds__(256) void attn_main(
    const uint_t* __restrict__ maskw, const float* __restrict__ degf,
    const ushort_t* __restrict__ gq, const float* __restrict__ e1,
    const float* __restrict__ e2, float* __restrict__ out)
{
    __shared__ uint_t maskS[256 * 33];        // pad 33: bank = (row+mc)&31
    __shared__ __align__(16) float e2S[MM];
    __shared__ float e1S[256];
    __shared__ float degS[256];

    int b = blockIdx.y;
    int nb = blockIdx.x >> 1, dh = blockIdx.x & 1;
    int n0 = nb * 256;
    int t = threadIdx.x;
    int wid = t >> 6, lane = t & 63;
    int rlo = lane & 15, hh = lane >> 4;

    // ---- stage (once) ----
    *(float4*)(&e2S[t * 4]) = *(const float4*)(e2 + b * MM + t * 4);
    e1S[t]  = e1[b * NN + n0 + t];
    degS[t] = degf[b * NN + n0 + t];
    #pragma unroll
    for (int k = 0; k < 8; k++) {
        int wi = t + k * 256;                 // uint4 index 0..2047
        int row = wi >> 3, w0 = (wi & 7) * 4;
        uint4 mv = *(const uint4*)(maskw + (size_t)(b * NN + n0 + row) * 32 + w0);
        maskS[row * 33 + w0 + 0] = mv.x;
        maskS[row * 33 + w0 + 1] = mv.y;
        maskS[row * 33 + w0 + 2] = mv.z;
        maskS[row * 33 + w0 + 3] = mv.w;
    }
    __syncthreads();

    float e1r[4], zl[4] = {0.f, 0.f, 0.f, 0.f};
    #pragma unroll
    for (int f = 0; f < 4; f++) e1r[f] = e1S[wid * 64 + f * 16 + rlo];

    // gq: chunk stride DD*32 = 4096 shorts; in-chunk (dh*64 + j*16 + rlo)*32 + 8*hh
    const ushort_t* gb = gq + (size_t)b * (32 * DD * 32)
                       + dh * 2048 + rlo * 32 + 8 * hh;

    f32x4 acc[4][4];
    #pragma unroll
    for (int f = 0; f < 4; f++)
        #pragma unroll
        for (int j = 0; j < 4; j++) acc[f][j] = (f32x4){0.f, 0.f, 0.f, 0.f};

    bf16x8 cb[4];
    #pragma unroll
    for (int j = 0; j < 4; j++)
        cb[j] = __builtin_bit_cast(bf16x8, *(const int4*)(gb + j * 512));

    for (int mc = 0; mc < 32; ++mc) {
        bf16x8 pb[4];
        int mcn = (mc < 31) ? mc + 1 : 31;
        #pragma unroll
        for (int j = 0; j < 4; j++)
            pb[j] = __builtin_bit_cast(bf16x8,
                    *(const int4*)(gb + (size_t)mcn * 4096 + j * 512));

        float4 ev0 = *(const float4*)(&e2S[mc * 32 + 8 * hh]);
        float4 ev1 = *(const float4*)(&e2S[mc * 32 + 8 * hh + 4]);
        float ex[8] = {ev0.x, ev0.y, ev0.z, ev0.w, ev1.x, ev1.y, ev1.z, ev1.w};

        #pragma unroll
        for (int f = 0; f < 4; f++) {
            uint_t mw = maskS[(wid * 64 + f * 16 + rlo) * 33 + mc];
            uint_t byte = (mw >> (8 * hh)) & 0xffu;
            bf16x8 af;
            #pragma unroll
            for (int jj = 0; jj < 8; jj++) {
                float s = leaky(e1r[f] + ex[jj]) - CBOUND;
                float wv = ((byte >> jj) & 1u) ? __expf(s) : 0.f;
                zl[f] += wv;
                af[jj] = (__bf16)wv;
            }
            #pragma unroll
            for (int j = 0; j < 4; j++)
                acc[f][j] = __builtin_amdgcn_mfma_f32_16x16x32_bf16(
                                af, cb[j], acc[f][j], 0, 0, 0);
        }
        #pragma unroll
        for (int j = 0; j < 4; j++) cb[j] = pb[j];
    }

    // per-row Z: lanes sharing rlo hold partials -> reduce over lane bits 4,5
    #pragma unroll
    for (int f = 0; f < 4; f++) {
        zl[f] += __shfl_xor(zl[f], 16);
        zl[f] += __shfl_xor(zl[f], 32);
    }

    // C layout: col = rlo, row(within frag) = 4*hh + rg
    float* ob = out + ((size_t)(b * NN + n0 + wid * 64)) * DD + dh * 64 + rlo;
    #pragma unroll
    for (int f = 0; f < 4; f++)
        #pragma unroll
        for (int rg = 0; rg < 4; rg++) {
            int row = f * 16 + 4 * hh + rg;
            float Z  = __shfl(zl[f], 4 * hh + rg);
            float dg = degS[wid * 64 + row];
            float sc = (dg > 0.f) ? (dg / Z) : 0.f;
            #pragma unroll
            for (int j = 0; j < 4; j++)
                ob[(size_t)row * DD + j * 16] = acc[f][j][rg] * sc;
        }
}

extern "C" void kernel_launch(void* const* d_in, const int* in_sizes, int n_in,
                              void* d_out, int out_size, void* d_ws, size_t ws_size,
                              hipStream_t stream) {
    const float* h   = (const float*)d_in[0];
    const float* g   = (const float*)d_in[1];
    const int*   adj = (const int*)d_in[2];
    const float* a1  = (const float*)d_in[3];
    const float* a2  = (const float*)d_in[4];
    float* out = (float*)d_out;

    // workspace layout (bytes):
    // e1   @ 0       : 128 KB
    // e2   @ 128 KB  : 128 KB
    // degf @ 256 KB  : 128 KB
    // mask @ 384 KB  : 4 MB
    // gq   @ ~4.4 MB : 8 MB
    char* ws = (char*)d_ws;
    float*    e1   = (float*)(ws);
    float*    e2   = (float*)(ws + (128u << 10));
    float*    degf = (float*)(ws + (256u << 10));
    uint_t*   mask = (uint_t*)(ws + (384u << 10));
    ushort_t* gq   = (ushort_t*)(ws + (384u << 10) + (4u << 20));

    pack_adj_e1<<<dim3(BB * NN / 4), 256, 0, stream>>>(adj, h, a1, mask, degf, e1);
    transpose_pack_g<<<dim3(MM / 64, BB), 256, 0, stream>>>(g, a2, gq, e2);
    attn_main<<<dim3(8, BB), 256, 0, stream>>>(mask, degf, gq, e1, e2, out);
}

// Round 6
// 67.412 us; speedup vs baseline: 1.7605x; 1.0023x over previous
//
#include <hip/hip_runtime.h>

#define BB 32
#define NN 1024
#define MM 1024
#define DD 128

typedef __attribute__((ext_vector_type(4))) float f32x4;
typedef __attribute__((ext_vector_type(8))) __bf16 bf16x8;
typedef unsigned short ushort_t;
typedef unsigned int uint_t;

#define L2E 1.44269504f
#define KEXP 9.357623e-14f   // exp(-30): folded softmax shift

__device__ __forceinline__ unsigned f2bf(float x) {
    unsigned u = __builtin_bit_cast(unsigned, x);
    return (u + 0x7fffu + ((u >> 16) & 1u)) >> 16;  // RNE bf16, finite inputs
}

// ---- Kernel 1: adj row -> bitmask + degree ; e1[b,n] = h row · a1 (fused) ---
__global__ __launch_bounds__(256) void pack_adj_e1(
    const int* __restrict__ adj, const float* __restrict__ h,
    const float* __restrict__ a1,
    uint_t* __restrict__ maskw, float* __restrict__ degf,
    float* __restrict__ e1)
{
    int wave = (blockIdx.x * 256 + threadIdx.x) >> 6;  // row id 0..32767
    int lane = threadIdx.x & 63;
    const int* ap = adj + (size_t)wave * MM + lane * 4;
    int4 v[4];
    #pragma unroll
    for (int r = 0; r < 4; r++) v[r] = *(const int4*)(ap + r * 256);
    float2 x = *(const float2*)(h + (size_t)wave * DD + lane * 2);
    float2 a = *(const float2*)(a1 + lane * 2);
    float p = x.x * a.x + x.y * a.y;
    int cnt = 0;
    #pragma unroll
    for (int r = 0; r < 4; r++) {
        uint_t nib = (v[r].x > 0 ? 1u : 0u) | (v[r].y > 0 ? 2u : 0u)
                   | (v[r].z > 0 ? 4u : 0u) | (v[r].w > 0 ? 8u : 0u);
        cnt += __popc(nib);
        uint_t val = nib << (4 * (lane & 7));
        val |= __shfl_xor(val, 1);
        val |= __shfl_xor(val, 2);
        val |= __shfl_xor(val, 4);
        if ((lane & 7) == 0) maskw[(size_t)wave * 32 + r * 8 + (lane >> 3)] = val;
    }
    #pragma unroll
    for (int s = 32; s; s >>= 1) {
        cnt += __shfl_xor(cnt, s);
        p   += __shfl_xor(p, s);
    }
    if (lane == 0) { degf[wave] = (float)cnt; e1[wave] = p; }
}

// ---- Kernel 2: gq[b][mc][d][mm] = bf16(g[b][m][d]) ; e2 = g·a2 (fused) ------
__global__ __launch_bounds__(256) void transpose_pack_g(
    const float* __restrict__ g, const float* __restrict__ a2,
    ushort_t* __restrict__ gq, float* __restrict__ e2)
{
    __shared__ ushort_t tl[DD][66];
    int b = blockIdx.y, m0 = blockIdx.x * 64, t = threadIdx.x;
    #pragma unroll
    for (int i = 0; i < 8; i++) {
        int idx = i * 256 + t;
        int m = idx >> 5;            // local m 0..63 (32 consecutive lanes share m)
        int c4 = (idx & 31) * 4;     // d col 0..124
        float4 v = *(const float4*)(g + ((size_t)(b * MM + m0 + m)) * DD + c4);
        tl[c4 + 0][m] = (ushort_t)f2bf(v.x);
        tl[c4 + 1][m] = (ushort_t)f2bf(v.y);
        tl[c4 + 2][m] = (ushort_t)f2bf(v.z);
        tl[c4 + 3][m] = (ushort_t)f2bf(v.w);
        float4 av = *(const float4*)(a2 + c4);
        float p = v.x * av.x + v.y * av.y + v.z * av.z + v.w * av.w;
        #pragma unroll
        for (int s = 16; s; s >>= 1) p += __shfl_xor(p, s);
        if ((t & 31) == 0) e2[b * MM + m0 + m] = p;
    }
    __syncthreads();
    #pragma unroll
    for (int i = 0; i < 4; i++) {
        int idx = i * 256 + t;
        int d = idx >> 3;            // 0..127
        int c = (idx & 7) * 8;       // local m group 0..56
        int4 o;
        o.x = (int)((unsigned)tl[d][c + 0] | ((unsigned)tl[d][c + 1] << 16));
        o.y = (int)((unsigned)tl[d][c + 2] | ((unsigned)tl[d][c + 3] << 16));
        o.z = (int)((unsigned)tl[d][c + 4] | ((unsigned)tl[d][c + 5] << 16));
        o.w = (int)((unsigned)tl[d][c + 6] | ((unsigned)tl[d][c + 7] << 16));
        int mg = m0 + c;
        *(int4*)(gq + (((size_t)((b * 32 + (mg >> 5)) * DD + d)) << 5) + (mg & 31)) = o;
    }
}

// ---- Kernel 3: fused softmax + PV -------------------------------------------
// block = 4 waves: 64 rows x 128 d; wave (wr,wd) = 32 rows x 64 d.
// 512 blocks -> 2048 waves = 2/SIMD (latency hiding), gq traffic 268 MB (L2/L3).
// exp2-domain softmax: e1/e2 pre-scaled by log2(e); leaky is +homogeneous.
__global__ __launch_bounds__(256, 2) void attn_main(
    const uint_t* __restrict__ maskw, const float* __restrict__ degf,
    const ushort_t* __restrict__ gq, const float* __restrict__ e1,
    const float* __restrict__ e2, float* __restrict__ out)
{
    __shared__ uint_t maskS[64 * 33];         // pad 33: bank-conflict-free
    __shared__ __align__(16) float e2S[MM];
    __shared__ float e1S[64];
    __shared__ float degS[64];

    int b = blockIdx.y;
    int n0 = blockIdx.x * 64;
    int t = threadIdx.x;
    int wid = t >> 6, lane = t & 63;
    int wr = wid >> 1, wd = wid & 1;
    int rlo = lane & 15, hh = lane >> 4;

    // ---- stage (once) ----
    {
        float4 ev = *(const float4*)(e2 + b * MM + t * 4);
        ev.x *= L2E; ev.y *= L2E; ev.z *= L2E; ev.w *= L2E;
        *(float4*)(&e2S[t * 4]) = ev;
    }
    if (t < 64) {
        e1S[t]  = L2E * e1[b * NN + n0 + t];
        degS[t] = degf[b * NN + n0 + t];
    }
    #pragma unroll
    for (int k = 0; k < 2; k++) {
        int wi = t + k * 256;                 // uint4 index 0..511
        int row = wi >> 3, w0 = (wi & 7) * 4;
        uint4 mv = *(const uint4*)(maskw + (size_t)(b * NN + n0 + row) * 32 + w0);
        maskS[row * 33 + w0 + 0] = mv.x;
        maskS[row * 33 + w0 + 1] = mv.y;
        maskS[row * 33 + w0 + 2] = mv.z;
        maskS[row * 33 + w0 + 3] = mv.w;
    }
    __syncthreads();

    float e1f[2], zl[2] = {0.f, 0.f};
    #pragma unroll
    for (int f = 0; f < 2; f++) e1f[f] = e1S[wr * 32 + f * 16 + rlo];

    // gq chunk stride = DD*32 = 4096 shorts; in-chunk (wd*64 + j*16 + rlo)*32 + 8*hh
    const ushort_t* gb = gq + (size_t)b * (32 * DD * 32)
                       + wd * 2048 + rlo * 32 + 8 * hh;

    f32x4 acc[2][4];
    #pragma unroll
    for (int f = 0; f < 2; f++)
        #pragma unroll
        for (int j = 0; j < 4; j++) acc[f][j] = (f32x4){0.f, 0.f, 0.f, 0.f};

    bf16x8 cb[4];
    #pragma unroll
    for (int j = 0; j < 4; j++)
        cb[j] = __builtin_bit_cast(bf16x8, *(const int4*)(gb + j * 512));

    for (int mc = 0; mc < 32; ++mc) {
        bf16x8 pb[4];
        int mcn = (mc < 31) ? mc + 1 : 31;
        #pragma unroll
        for (int j = 0; j < 4; j++)
            pb[j] = __builtin_bit_cast(bf16x8,
                    *(const int4*)(gb + (size_t)mcn * 4096 + j * 512));

        float4 ev0 = *(const float4*)(&e2S[mc * 32 + 8 * hh]);
        float4 ev1 = *(const float4*)(&e2S[mc * 32 + 8 * hh + 4]);
        float ex[8] = {ev0.x, ev0.y, ev0.z, ev0.w, ev1.x, ev1.y, ev1.z, ev1.w};

        #pragma unroll
        for (int f = 0; f < 2; f++) {
            uint_t mw = maskS[(wr * 32 + f * 16 + rlo) * 33 + mc];
            uint_t byte = (mw >> (8 * hh)) & 0xffu;
            bf16x8 af;
            #pragma unroll
            for (int jj = 0; jj < 8; jj++) {
                float sp = e1f[f] + ex[jj];            // log2-domain score
                float lk = fmaxf(sp, 0.2f * sp);       // leaky (homogeneous)
                float sel = ((byte >> jj) & 1u) ? KEXP : 0.f;
                float wv = sel * __builtin_amdgcn_exp2f(lk);
                zl[f] += wv;
                af[jj] = (__bf16)wv;
            }
            #pragma unroll
            for (int j = 0; j < 4; j++)
                acc[f][j] = __builtin_amdgcn_mfma_f32_16x16x32_bf16(
                                af, cb[j], acc[f][j], 0, 0, 0);
        }
        #pragma unroll
        for (int j = 0; j < 4; j++) cb[j] = pb[j];
    }

    // per-row Z: lanes sharing rlo hold partials -> reduce over lane bits 4,5
    #pragma unroll
    for (int f = 0; f < 2; f++) {
        zl[f] += __shfl_xor(zl[f], 16);
        zl[f] += __shfl_xor(zl[f], 32);
    }

    // C layout: col = rlo, row(within frag) = 4*hh + rg
    float* ob = out + ((size_t)(b * NN + n0 + wr * 32)) * DD + wd * 64 + rlo;
    #pragma unroll
    for (int f = 0; f < 2; f++)
        #pragma unroll
        for (int rg = 0; rg < 4; rg++) {
            int row = f * 16 + 4 * hh + rg;
            float Z  = __shfl(zl[f], 4 * hh + rg);
            float dg = degS[wr * 32 + row];
            float sc = (dg > 0.f) ? (dg / Z) : 0.f;
            #pragma unroll
            for (int j = 0; j < 4; j++)
                ob[(size_t)row * DD + j * 16] = acc[f][j][rg] * sc;
        }
}

extern "C" void kernel_launch(void* const* d_in, const int* in_sizes, int n_in,
                              void* d_out, int out_size, void* d_ws, size_t ws_size,
                              hipStream_t stream) {
    const float* h   = (const float*)d_in[0];
    const float* g   = (const float*)d_in[1];
    const int*   adj = (const int*)d_in[2];
    const float* a1  = (const float*)d_in[3];
    const float* a2  = (const float*)d_in[4];
    float* out = (float*)d_out;

    char* ws = (char*)d_ws;
    float*    e1   = (float*)(ws);
    float*    e2   = (float*)(ws + (128u << 10));
    float*    degf = (float*)(ws + (256u << 10));
    uint_t*   mask = (uint_t*)(ws + (384u << 10));
    ushort_t* gq   = (ushort_t*)(ws + (384u << 10) + (4u << 20));

    pack_adj_e1<<<dim3(BB * NN / 4), 256, 0, stream>>>(adj, h, a1, mask, degf, e1);
    transpose_pack_g<<<dim3(MM / 64, BB), 256, 0, stream>>>(g, a2, gq, e2);
    attn_main<<<dim3(NN / 64, BB), 256, 0, stream>>>(mask, degf, gq, e1, e2, out);
}

// Round 7
// 66.215 us; speedup vs baseline: 1.7923x; 1.0181x over previous
//
#include <hip/hip_runtime.h>

#define BB 32
#define NN 1024
#define MM 1024
#define DD 128

typedef __attribute__((ext_vector_type(4))) float f32x4;
typedef __attribute__((ext_vector_type(8))) __bf16 bf16x8;
typedef unsigned short ushort_t;
typedef unsigned int uint_t;

#define L2E 1.44269504f
#define KEXP 9.357623e-14f      // exp(-30): folded softmax shift
#define KEXPINV 1.0686475e13f   // exp(+30)

__device__ __forceinline__ unsigned f2bf(float x) {
    unsigned u = __builtin_bit_cast(unsigned, x);
    return (u + 0x7fffu + ((u >> 16) & 1u)) >> 16;  // RNE bf16, finite inputs
}

// ---- Kernel 1 (prep): gq = bf16(g)^T tiles ; e2 = g·a2 ; e1 = h·a1 ----------
__global__ __launch_bounds__(256) void prep(
    const float* __restrict__ g, const float* __restrict__ h,
    const float* __restrict__ a1, const float* __restrict__ a2,
    ushort_t* __restrict__ gq, float* __restrict__ e1, float* __restrict__ e2)
{
    __shared__ ushort_t tl[DD][66];  // +2 pad breaks write bank conflicts
    int b = blockIdx.y, m0 = blockIdx.x * 64, t = threadIdx.x;

    // e1 for 64 h-rows (same row-dot pattern as e2 below)
    #pragma unroll
    for (int i = 0; i < 8; i++) {
        int idx = i * 256 + t;
        int m = idx >> 5;            // 32 consecutive lanes share row m
        int c4 = (idx & 31) * 4;
        float4 v = *(const float4*)(h + ((size_t)(b * NN + m0 + m)) * DD + c4);
        float4 av = *(const float4*)(a1 + c4);
        float p = v.x * av.x + v.y * av.y + v.z * av.z + v.w * av.w;
        #pragma unroll
        for (int s = 16; s; s >>= 1) p += __shfl_xor(p, s);
        if ((t & 31) == 0) e1[b * NN + m0 + m] = p;
    }
    // g transpose -> LDS (+ e2 dot)
    #pragma unroll
    for (int i = 0; i < 8; i++) {
        int idx = i * 256 + t;
        int m = idx >> 5;
        int c4 = (idx & 31) * 4;
        float4 v = *(const float4*)(g + ((size_t)(b * MM + m0 + m)) * DD + c4);
        tl[c4 + 0][m] = (ushort_t)f2bf(v.x);
        tl[c4 + 1][m] = (ushort_t)f2bf(v.y);
        tl[c4 + 2][m] = (ushort_t)f2bf(v.z);
        tl[c4 + 3][m] = (ushort_t)f2bf(v.w);
        float4 av = *(const float4*)(a2 + c4);
        float p = v.x * av.x + v.y * av.y + v.z * av.z + v.w * av.w;
        #pragma unroll
        for (int s = 16; s; s >>= 1) p += __shfl_xor(p, s);
        if ((t & 31) == 0) e2[b * MM + m0 + m] = p;
    }
    __syncthreads();
    // LDS -> gq tiles [b][mc][d][m&31]
    #pragma unroll
    for (int i = 0; i < 4; i++) {
        int idx = i * 256 + t;
        int d = idx >> 3;            // 0..127
        int c = (idx & 7) * 8;       // local m group
        int4 o;
        o.x = (int)((unsigned)tl[d][c + 0] | ((unsigned)tl[d][c + 1] << 16));
        o.y = (int)((unsigned)tl[d][c + 2] | ((unsigned)tl[d][c + 3] << 16));
        o.z = (int)((unsigned)tl[d][c + 4] | ((unsigned)tl[d][c + 5] << 16));
        o.w = (int)((unsigned)tl[d][c + 6] | ((unsigned)tl[d][c + 7] << 16));
        int mg = m0 + c;
        *(int4*)(gq + (((size_t)((b * 32 + (mg >> 5)) * DD + d)) << 5) + (mg & 31)) = o;
    }
}

// ---- Kernel 2: fully fused adj-stream + softmax + PV ------------------------
// block = 4 waves x 16 rows = 64 rows, all 128 d. Lane owns its A-fragment:
// row = lane&15, k = 8*(lane>>4)+jj -> reads its own 8 adj words per chunk.
// adj read ONCE from HBM (128 MB), depth-2 register prefetch keeps
// 8 waves/CU x 4 KB = 32 KB in flight (saturates HBM). gq is L2-resident.
__global__ __launch_bounds__(256, 2) void attn_fused(
    const int* __restrict__ adj, const ushort_t* __restrict__ gq,
    const float* __restrict__ e1, const float* __restrict__ e2,
    float* __restrict__ out)
{
    __shared__ __align__(16) float e2S[MM];
    int b = blockIdx.y, n0 = blockIdx.x * 64, t = threadIdx.x;
    int wid = t >> 6, lane = t & 63;
    int rlo = lane & 15, hh = lane >> 4;
    int row = n0 + wid * 16 + rlo;

    {
        float4 ev = *(const float4*)(e2 + b * MM + t * 4);
        ev.x *= L2E; ev.y *= L2E; ev.z *= L2E; ev.w *= L2E;
        *(float4*)(&e2S[t * 4]) = ev;
    }
    __syncthreads();

    float e1f = L2E * e1[b * NN + row];

    const int* ap = adj + (size_t)(b * NN + row) * MM + 8 * hh;
    const ushort_t* gb = gq + (size_t)b * (32 * DD * 32) + rlo * 32 + 8 * hh;

    f32x4 acc[8];
    #pragma unroll
    for (int j = 0; j < 8; j++) acc[j] = (f32x4){0.f, 0.f, 0.f, 0.f};
    float zl = 0.f, dl = 0.f;

    // depth-2 adj prefetch: ca = mc, na = mc+1, pa = mc+2
    int4 ca0 = *(const int4*)(ap);
    int4 ca1 = *(const int4*)(ap + 4);
    int4 na0 = *(const int4*)(ap + 32);
    int4 na1 = *(const int4*)(ap + 36);

    for (int mc = 0; mc < 32; ++mc) {
        int mcn = (mc < 30) ? (mc + 2) : 31;
        int4 pa0 = *(const int4*)(ap + mcn * 32);
        int4 pa1 = *(const int4*)(ap + mcn * 32 + 4);

        // B fragments for current chunk (L2-resident; hidden under softmax)
        bf16x8 cb[8];
        const ushort_t* gt = gb + (size_t)mc * 4096;
        #pragma unroll
        for (int j = 0; j < 8; j++)
            cb[j] = __builtin_bit_cast(bf16x8, *(const int4*)(gt + j * 512));

        float4 ev0 = *(const float4*)(&e2S[mc * 32 + 8 * hh]);
        float4 ev1 = *(const float4*)(&e2S[mc * 32 + 8 * hh + 4]);
        float ex[8] = {ev0.x, ev0.y, ev0.z, ev0.w, ev1.x, ev1.y, ev1.z, ev1.w};
        int   ax[8] = {ca0.x, ca0.y, ca0.z, ca0.w, ca1.x, ca1.y, ca1.z, ca1.w};

        bf16x8 af;
        #pragma unroll
        for (int jj = 0; jj < 8; jj++) {
            float sp = e1f + ex[jj];              // log2-domain score
            float lk = fmaxf(sp, 0.2f * sp);      // leaky (pos-homogeneous)
            float sel = (ax[jj] > 0) ? KEXP : 0.f;
            float wv = sel * __builtin_amdgcn_exp2f(lk);
            zl += wv;
            dl += sel;                             // deg * KEXP (exact)
            af[jj] = (__bf16)wv;
        }
        #pragma unroll
        for (int j = 0; j < 8; j++)
            acc[j] = __builtin_amdgcn_mfma_f32_16x16x32_bf16(af, cb[j], acc[j], 0, 0, 0);

        ca0 = na0; ca1 = na1; na0 = pa0; na1 = pa1;
    }

    // per-row Z, deg: lanes sharing rlo hold partials -> reduce lane bits 4,5
    zl += __shfl_xor(zl, 16); zl += __shfl_xor(zl, 32);
    dl += __shfl_xor(dl, 16); dl += __shfl_xor(dl, 32);
    float sc = (dl > 0.f) ? (dl * KEXPINV) / zl : 0.f;   // = deg / Z

    float scr[4];
    #pragma unroll
    for (int rg = 0; rg < 4; rg++) scr[rg] = __shfl(sc, 4 * hh + rg);

    // C layout: col = rlo, row(within frag) = 4*hh + rg
    float* ob = out + ((size_t)(b * NN + n0 + wid * 16)) * DD + rlo;
    #pragma unroll
    for (int j = 0; j < 8; j++)
        #pragma unroll
        for (int rg = 0; rg < 4; rg++)
            ob[(size_t)(4 * hh + rg) * DD + j * 16] = acc[j][rg] * scr[rg];
}

extern "C" void kernel_launch(void* const* d_in, const int* in_sizes, int n_in,
                              void* d_out, int out_size, void* d_ws, size_t ws_size,
                              hipStream_t stream) {
    const float* h   = (const float*)d_in[0];
    const float* g   = (const float*)d_in[1];
    const int*   adj = (const int*)d_in[2];
    const float* a1  = (const float*)d_in[3];
    const float* a2  = (const float*)d_in[4];
    float* out = (float*)d_out;

    // workspace: e1 @0 (128 KB), e2 @128 KB (128 KB), gq @512 KB (8 MB)
    char* ws = (char*)d_ws;
    float*    e1 = (float*)(ws);
    float*    e2 = (float*)(ws + (128u << 10));
    ushort_t* gq = (ushort_t*)(ws + (512u << 10));

    prep<<<dim3(MM / 64, BB), 256, 0, stream>>>(g, h, a1, a2, gq, e1, e2);
    attn_fused<<<dim3(NN / 64, BB), 256, 0, stream>>>(adj, gq, e1, e2, out);
}